// Round 1
// baseline (2845.012 us; speedup 1.0000x reference)
//
#include <hip/hip_runtime.h>

#define NN 50000
#define NE 800000
#define DIM 128

// ---------------- scatter-add: aggr[dst[e]] += x[src[e]] ----------------
// one thread per (edge, float4-chunk); 32 chunks cover 128 floats
__global__ __launch_bounds__(256)
void scatter_add_kernel(const float* __restrict__ x,
                        const int* __restrict__ src,
                        const int* __restrict__ dst,
                        float* __restrict__ aggr) {
    int idx = blockIdx.x * 256 + threadIdx.x;   // e*32 + c
    int e = idx >> 5;
    int c = idx & 31;
    if (e >= NE) return;
    int s = src[e];
    int d = dst[e];
    const float4 v = ((const float4*)x)[(size_t)s * 32 + c];
    float* out = aggr + (size_t)d * DIM + c * 4;
    atomicAdd(out + 0, v.x);
    atomicAdd(out + 1, v.y);
    atomicAdd(out + 2, v.z);
    atomicAdd(out + 3, v.w);
}

// ---------------- fused graph-conv GEMM ----------------
// Out[n][o] = relu( sum_k Aggr[n][k]*Wrel[o][k] + X[n][k]*Wroot[o][k] + bias[o] )
// tile: 64 nodes x 128 outs, 256 threads, each thread 4 nodes x 8 outs
__global__ __launch_bounds__(256)
void conv_kernel(const float* __restrict__ Aggr,
                 const float* __restrict__ X,
                 const float* __restrict__ Wrel,
                 const float* __restrict__ Wroot,
                 const float* __restrict__ bias,
                 float* __restrict__ Out) {
    __shared__ __align__(16) float As[32][68];    // [kk][m]  (68: 16B-aligned rows, low conflict)
    __shared__ __align__(16) float Bs[32][132];   // [kk][o]
    const int tid = threadIdx.x;
    const int tm = tid >> 4;       // 0..15 -> node group of 4
    const int tn = tid & 15;       // 0..15 -> out group of 8
    const int m_blk = blockIdx.x * 64;

    float acc[4][8];
#pragma unroll
    for (int i = 0; i < 4; ++i)
#pragma unroll
        for (int j = 0; j < 8; ++j) acc[i][j] = 0.f;

    const int lr = tid >> 3;        // 0..31
    const int lc = (tid & 7) * 4;   // 0,4,...,28

    for (int mat = 0; mat < 2; ++mat) {
        const float* A = mat ? X : Aggr;
        const float* W = mat ? Wroot : Wrel;
        for (int kb = 0; kb < 128; kb += 32) {
            __syncthreads();
            // stage A chunk transposed: As[kk][m]
#pragma unroll
            for (int rr = 0; rr < 2; ++rr) {
                int m = lr + rr * 32;
                int gm = m_blk + m;
                float4 v = make_float4(0.f, 0.f, 0.f, 0.f);
                if (gm < NN) v = *(const float4*)(A + (size_t)gm * DIM + kb + lc);
                As[lc + 0][m] = v.x;
                As[lc + 1][m] = v.y;
                As[lc + 2][m] = v.z;
                As[lc + 3][m] = v.w;
            }
            // stage W chunk transposed: Bs[kk][o], all 128 o rows
#pragma unroll
            for (int rr = 0; rr < 4; ++rr) {
                int o = lr + rr * 32;
                float4 v = *(const float4*)(W + (size_t)o * DIM + kb + lc);
                Bs[lc + 0][o] = v.x;
                Bs[lc + 1][o] = v.y;
                Bs[lc + 2][o] = v.z;
                Bs[lc + 3][o] = v.w;
            }
            __syncthreads();
#pragma unroll
            for (int kk = 0; kk < 32; ++kk) {
                float4 a4 = *(const float4*)&As[kk][tm * 4];
                float4 b0 = *(const float4*)&Bs[kk][tn * 8];
                float4 b1 = *(const float4*)&Bs[kk][tn * 8 + 4];
                float a[4] = {a4.x, a4.y, a4.z, a4.w};
                float b[8] = {b0.x, b0.y, b0.z, b0.w, b1.x, b1.y, b1.z, b1.w};
#pragma unroll
                for (int i = 0; i < 4; ++i)
#pragma unroll
                    for (int j = 0; j < 8; ++j)
                        acc[i][j] += a[i] * b[j];
            }
        }
    }
    // epilogue: bias + relu, vectorized stores
    float4 bia0 = *(const float4*)(bias + tn * 8);
    float4 bia1 = *(const float4*)(bias + tn * 8 + 4);
#pragma unroll
    for (int i = 0; i < 4; ++i) {
        int gm = m_blk + tm * 4 + i;
        if (gm >= NN) continue;
        float4 v0, v1;
        v0.x = fmaxf(acc[i][0] + bia0.x, 0.f);
        v0.y = fmaxf(acc[i][1] + bia0.y, 0.f);
        v0.z = fmaxf(acc[i][2] + bia0.z, 0.f);
        v0.w = fmaxf(acc[i][3] + bia0.w, 0.f);
        v1.x = fmaxf(acc[i][4] + bia1.x, 0.f);
        v1.y = fmaxf(acc[i][5] + bia1.y, 0.f);
        v1.z = fmaxf(acc[i][6] + bia1.z, 0.f);
        v1.w = fmaxf(acc[i][7] + bia1.w, 0.f);
        *(float4*)(Out + (size_t)gm * DIM + tn * 8) = v0;
        *(float4*)(Out + (size_t)gm * DIM + tn * 8 + 4) = v1;
    }
}

// ---------------- fused agent MLP ----------------
// 8 agents per block, 256 threads
__global__ __launch_bounds__(256)
void mlp_kernel(const float* __restrict__ Z,
                const int* __restrict__ agent_idx,
                const float* __restrict__ Wp1, const float* __restrict__ bp1,
                const float* __restrict__ Wp2, const float* __restrict__ bp2,
                const float* __restrict__ Wp3, const float* __restrict__ bp3,
                float* __restrict__ Out) {
    __shared__ __align__(16) float sel[8][132];
    __shared__ __align__(16) float m1[8][132];
    __shared__ __align__(16) float m2[8][132];
    const int tid = threadIdx.x;
    const int ab = blockIdx.x * 8;

    {   // gather selected node embeddings
        int al = tid >> 5;            // 0..7
        int c = (tid & 31) * 4;
        int node = agent_idx[ab + al];
        float4 v = *(const float4*)(Z + (size_t)node * DIM + c);
        sel[al][c + 0] = v.x; sel[al][c + 1] = v.y;
        sel[al][c + 2] = v.z; sel[al][c + 3] = v.w;
    }
    __syncthreads();
    {   // layer 1: m1 = relu(sel @ Wp1^T + bp1)
        int o = tid & 127;
        int g = tid >> 7;   // 0..1
        float acc[4] = {0.f, 0.f, 0.f, 0.f};
        for (int k = 0; k < 128; k += 4) {
            float4 w = *(const float4*)(Wp1 + (size_t)o * 128 + k);
#pragma unroll
            for (int a = 0; a < 4; ++a) {
                int aa = g * 4 + a;
                acc[a] += w.x * sel[aa][k] + w.y * sel[aa][k + 1]
                        + w.z * sel[aa][k + 2] + w.w * sel[aa][k + 3];
            }
        }
        float b = bp1[o];
#pragma unroll
        for (int a = 0; a < 4; ++a) m1[g * 4 + a][o] = fmaxf(acc[a] + b, 0.f);
    }
    __syncthreads();
    {   // layer 2: m2 = relu(m1 @ Wp2^T + bp2)
        int o = tid & 127;
        int g = tid >> 7;
        float acc[4] = {0.f, 0.f, 0.f, 0.f};
        for (int k = 0; k < 128; k += 4) {
            float4 w = *(const float4*)(Wp2 + (size_t)o * 128 + k);
#pragma unroll
            for (int a = 0; a < 4; ++a) {
                int aa = g * 4 + a;
                acc[a] += w.x * m1[aa][k] + w.y * m1[aa][k + 1]
                        + w.z * m1[aa][k + 2] + w.w * m1[aa][k + 3];
            }
        }
        float b = bp2[o];
#pragma unroll
        for (int a = 0; a < 4; ++a) m2[g * 4 + a][o] = fmaxf(acc[a] + b, 0.f);
    }
    __syncthreads();
    {   // layer 3: traj = m2 @ Wp3^T + bp3   (512 outputs)
#pragma unroll
        for (int oo = 0; oo < 2; ++oo) {
            int o = tid + oo * 256;
            float acc[8] = {0.f, 0.f, 0.f, 0.f, 0.f, 0.f, 0.f, 0.f};
            for (int k = 0; k < 128; k += 4) {
                float4 w = *(const float4*)(Wp3 + (size_t)o * 128 + k);
#pragma unroll
                for (int a = 0; a < 8; ++a) {
                    acc[a] += w.x * m2[a][k] + w.y * m2[a][k + 1]
                            + w.z * m2[a][k + 2] + w.w * m2[a][k + 3];
                }
            }
            float b = bp3[o];
#pragma unroll
            for (int a = 0; a < 8; ++a)
                Out[(size_t)(ab + a) * 512 + o] = acc[a] + b;
        }
    }
}

extern "C" void kernel_launch(void* const* d_in, const int* in_sizes, int n_in,
                              void* d_out, int out_size, void* d_ws, size_t ws_size,
                              hipStream_t stream) {
    const float* x       = (const float*)d_in[0];
    const int*   edge    = (const int*)d_in[1];   // JAX x64 disabled -> int32
    const int*   src     = edge;                  // edge_index[0]
    const int*   dst     = edge + NE;             // edge_index[1]
    const int*   agent   = (const int*)d_in[2];
    const float* W1_rel  = (const float*)d_in[3];
    const float* b1_rel  = (const float*)d_in[4];
    const float* W1_root = (const float*)d_in[5];
    const float* W2_rel  = (const float*)d_in[6];
    const float* b2_rel  = (const float*)d_in[7];
    const float* W2_root = (const float*)d_in[8];
    const float* Wp1     = (const float*)d_in[9];
    const float* bp1     = (const float*)d_in[10];
    const float* Wp2     = (const float*)d_in[11];
    const float* bp2     = (const float*)d_in[12];
    const float* Wp3     = (const float*)d_in[13];
    const float* bp3     = (const float*)d_in[14];
    float* out = (float*)d_out;

    float* ws   = (float*)d_ws;
    float* aggr = ws;                          // 50000*128 floats (reused for conv2)
    float* h    = ws + (size_t)NN * DIM;
    float* z    = ws + (size_t)2 * NN * DIM;
    const size_t aggr_bytes = (size_t)NN * DIM * sizeof(float);

    const int scat_blocks = (NE * 32) / 256;   // 100000
    const int conv_blocks = (NN + 63) / 64;    // 782

    // conv1
    hipMemsetAsync(aggr, 0, aggr_bytes, stream);
    scatter_add_kernel<<<scat_blocks, 256, 0, stream>>>(x, src, dst, aggr);
    conv_kernel<<<conv_blocks, 256, 0, stream>>>(aggr, x, W1_rel, W1_root, b1_rel, h);
    // conv2 (reuse aggr buffer)
    hipMemsetAsync(aggr, 0, aggr_bytes, stream);
    scatter_add_kernel<<<scat_blocks, 256, 0, stream>>>(h, src, dst, aggr);
    conv_kernel<<<conv_blocks, 256, 0, stream>>>(aggr, h, W2_rel, W2_root, b2_rel, z);
    // agent MLP
    mlp_kernel<<<1024 / 8, 256, 0, stream>>>(z, agent, Wp1, bp1, Wp2, bp2, Wp3, bp3, out);
}

// Round 2
// 462.794 us; speedup vs baseline: 6.1475x; 6.1475x over previous
//
#include <hip/hip_runtime.h>

#define NN 50000
#define NE 800000
#define DIM 128

// ---------------- CSR build ----------------
__global__ __launch_bounds__(256)
void hist_kernel(const int* __restrict__ dst, int* __restrict__ deg) {
    int e = blockIdx.x * 256 + threadIdx.x;
    if (e < NE) atomicAdd(&deg[dst[e]], 1);
}

// single-block exclusive scan over deg[0..NN) -> off[0..NN], also cursor=off
__global__ __launch_bounds__(1024)
void scan_kernel(const int* __restrict__ deg, int* __restrict__ off,
                 int* __restrict__ cursor) {
    __shared__ int s[1024];
    const int t = threadIdx.x;
    const int per = (NN + 1023) / 1024;   // 49
    const int base = t * per;
    int sum = 0;
    for (int i = 0; i < per; ++i) {
        int g = base + i;
        if (g < NN) sum += deg[g];
    }
    s[t] = sum;
    // Hillis-Steele inclusive scan
    for (int d = 1; d < 1024; d <<= 1) {
        __syncthreads();
        int v = (t >= d) ? s[t - d] : 0;
        __syncthreads();
        s[t] += v;
    }
    __syncthreads();
    int running = s[t] - sum;   // exclusive prefix
    for (int i = 0; i < per; ++i) {
        int g = base + i;
        if (g <= NN) {
            off[g] = running;
            if (g < NN) {
                cursor[g] = running;
                running += deg[g];
            }
        }
    }
}

__global__ __launch_bounds__(256)
void fill_kernel(const int* __restrict__ src, const int* __restrict__ dst,
                 int* __restrict__ cursor, int* __restrict__ eid) {
    int e = blockIdx.x * 256 + threadIdx.x;
    if (e >= NE) return;
    int pos = atomicAdd(&cursor[dst[e]], 1);
    eid[pos] = src[e];
}

// ---------------- gather-aggregate: aggr[n] = sum_{e: dst=n} x[src[e]] ----
// one wave (64 lanes) per node; lane handles a float2 chunk (64*8B = 512B row)
__global__ __launch_bounds__(256)
void gather_aggr_kernel(const float* __restrict__ x,
                        const int* __restrict__ off,
                        const int* __restrict__ eid,
                        float* __restrict__ aggr) {
    const int node = blockIdx.x * 4 + (threadIdx.x >> 6);
    const int lane = threadIdx.x & 63;
    const int s = off[node];
    const int e = off[node + 1];
    const float2* __restrict__ x2 = (const float2*)x;
    float2 acc = make_float2(0.f, 0.f);
    int i = s;
    for (; i + 4 <= e; i += 4) {
        int n0 = eid[i], n1 = eid[i + 1], n2 = eid[i + 2], n3 = eid[i + 3];
        float2 v0 = x2[(size_t)n0 * 64 + lane];
        float2 v1 = x2[(size_t)n1 * 64 + lane];
        float2 v2 = x2[(size_t)n2 * 64 + lane];
        float2 v3 = x2[(size_t)n3 * 64 + lane];
        acc.x += (v0.x + v1.x) + (v2.x + v3.x);
        acc.y += (v0.y + v1.y) + (v2.y + v3.y);
    }
    for (; i < e; ++i) {
        int n = eid[i];
        float2 v = x2[(size_t)n * 64 + lane];
        acc.x += v.x;
        acc.y += v.y;
    }
    ((float2*)aggr)[(size_t)node * 64 + lane] = acc;
}

// ---------------- fused graph-conv GEMM ----------------
// Out[n][o] = relu( sum_k Aggr[n][k]*Wrel[o][k] + X[n][k]*Wroot[o][k] + bias[o] )
__global__ __launch_bounds__(256)
void conv_kernel(const float* __restrict__ Aggr,
                 const float* __restrict__ X,
                 const float* __restrict__ Wrel,
                 const float* __restrict__ Wroot,
                 const float* __restrict__ bias,
                 float* __restrict__ Out) {
    __shared__ __align__(16) float As[32][68];
    __shared__ __align__(16) float Bs[32][132];
    const int tid = threadIdx.x;
    const int tm = tid >> 4;
    const int tn = tid & 15;
    const int m_blk = blockIdx.x * 64;

    float acc[4][8];
#pragma unroll
    for (int i = 0; i < 4; ++i)
#pragma unroll
        for (int j = 0; j < 8; ++j) acc[i][j] = 0.f;

    const int lr = tid >> 3;
    const int lc = (tid & 7) * 4;

    for (int mat = 0; mat < 2; ++mat) {
        const float* A = mat ? X : Aggr;
        const float* W = mat ? Wroot : Wrel;
        for (int kb = 0; kb < 128; kb += 32) {
            __syncthreads();
#pragma unroll
            for (int rr = 0; rr < 2; ++rr) {
                int m = lr + rr * 32;
                int gm = m_blk + m;
                float4 v = make_float4(0.f, 0.f, 0.f, 0.f);
                if (gm < NN) v = *(const float4*)(A + (size_t)gm * DIM + kb + lc);
                As[lc + 0][m] = v.x;
                As[lc + 1][m] = v.y;
                As[lc + 2][m] = v.z;
                As[lc + 3][m] = v.w;
            }
#pragma unroll
            for (int rr = 0; rr < 4; ++rr) {
                int o = lr + rr * 32;
                float4 v = *(const float4*)(W + (size_t)o * DIM + kb + lc);
                Bs[lc + 0][o] = v.x;
                Bs[lc + 1][o] = v.y;
                Bs[lc + 2][o] = v.z;
                Bs[lc + 3][o] = v.w;
            }
            __syncthreads();
#pragma unroll
            for (int kk = 0; kk < 32; ++kk) {
                float4 a4 = *(const float4*)&As[kk][tm * 4];
                float4 b0 = *(const float4*)&Bs[kk][tn * 8];
                float4 b1 = *(const float4*)&Bs[kk][tn * 8 + 4];
                float a[4] = {a4.x, a4.y, a4.z, a4.w};
                float b[8] = {b0.x, b0.y, b0.z, b0.w, b1.x, b1.y, b1.z, b1.w};
#pragma unroll
                for (int i = 0; i < 4; ++i)
#pragma unroll
                    for (int j = 0; j < 8; ++j)
                        acc[i][j] += a[i] * b[j];
            }
        }
    }
    float4 bia0 = *(const float4*)(bias + tn * 8);
    float4 bia1 = *(const float4*)(bias + tn * 8 + 4);
#pragma unroll
    for (int i = 0; i < 4; ++i) {
        int gm = m_blk + tm * 4 + i;
        if (gm >= NN) continue;
        float4 v0, v1;
        v0.x = fmaxf(acc[i][0] + bia0.x, 0.f);
        v0.y = fmaxf(acc[i][1] + bia0.y, 0.f);
        v0.z = fmaxf(acc[i][2] + bia0.z, 0.f);
        v0.w = fmaxf(acc[i][3] + bia0.w, 0.f);
        v1.x = fmaxf(acc[i][4] + bia1.x, 0.f);
        v1.y = fmaxf(acc[i][5] + bia1.y, 0.f);
        v1.z = fmaxf(acc[i][6] + bia1.z, 0.f);
        v1.w = fmaxf(acc[i][7] + bia1.w, 0.f);
        *(float4*)(Out + (size_t)gm * DIM + tn * 8) = v0;
        *(float4*)(Out + (size_t)gm * DIM + tn * 8 + 4) = v1;
    }
}

// ---------------- fused agent MLP ----------------
__global__ __launch_bounds__(256)
void mlp_kernel(const float* __restrict__ Z,
                const int* __restrict__ agent_idx,
                const float* __restrict__ Wp1, const float* __restrict__ bp1,
                const float* __restrict__ Wp2, const float* __restrict__ bp2,
                const float* __restrict__ Wp3, const float* __restrict__ bp3,
                float* __restrict__ Out) {
    __shared__ __align__(16) float sel[8][132];
    __shared__ __align__(16) float m1[8][132];
    __shared__ __align__(16) float m2[8][132];
    const int tid = threadIdx.x;
    const int ab = blockIdx.x * 8;

    {
        int al = tid >> 5;
        int c = (tid & 31) * 4;
        int node = agent_idx[ab + al];
        float4 v = *(const float4*)(Z + (size_t)node * DIM + c);
        sel[al][c + 0] = v.x; sel[al][c + 1] = v.y;
        sel[al][c + 2] = v.z; sel[al][c + 3] = v.w;
    }
    __syncthreads();
    {
        int o = tid & 127;
        int g = tid >> 7;
        float acc[4] = {0.f, 0.f, 0.f, 0.f};
        for (int k = 0; k < 128; k += 4) {
            float4 w = *(const float4*)(Wp1 + (size_t)o * 128 + k);
#pragma unroll
            for (int a = 0; a < 4; ++a) {
                int aa = g * 4 + a;
                acc[a] += w.x * sel[aa][k] + w.y * sel[aa][k + 1]
                        + w.z * sel[aa][k + 2] + w.w * sel[aa][k + 3];
            }
        }
        float b = bp1[o];
#pragma unroll
        for (int a = 0; a < 4; ++a) m1[g * 4 + a][o] = fmaxf(acc[a] + b, 0.f);
    }
    __syncthreads();
    {
        int o = tid & 127;
        int g = tid >> 7;
        float acc[4] = {0.f, 0.f, 0.f, 0.f};
        for (int k = 0; k < 128; k += 4) {
            float4 w = *(const float4*)(Wp2 + (size_t)o * 128 + k);
#pragma unroll
            for (int a = 0; a < 4; ++a) {
                int aa = g * 4 + a;
                acc[a] += w.x * m1[aa][k] + w.y * m1[aa][k + 1]
                        + w.z * m1[aa][k + 2] + w.w * m1[aa][k + 3];
            }
        }
        float b = bp2[o];
#pragma unroll
        for (int a = 0; a < 4; ++a) m2[g * 4 + a][o] = fmaxf(acc[a] + b, 0.f);
    }
    __syncthreads();
    {
#pragma unroll
        for (int oo = 0; oo < 2; ++oo) {
            int o = tid + oo * 256;
            float acc[8] = {0.f, 0.f, 0.f, 0.f, 0.f, 0.f, 0.f, 0.f};
            for (int k = 0; k < 128; k += 4) {
                float4 w = *(const float4*)(Wp3 + (size_t)o * 128 + k);
#pragma unroll
                for (int a = 0; a < 8; ++a) {
                    acc[a] += w.x * m2[a][k] + w.y * m2[a][k + 1]
                            + w.z * m2[a][k + 2] + w.w * m2[a][k + 3];
                }
            }
            float b = bp3[o];
#pragma unroll
            for (int a = 0; a < 8; ++a)
                Out[(size_t)(ab + a) * 512 + o] = acc[a] + b;
        }
    }
}

extern "C" void kernel_launch(void* const* d_in, const int* in_sizes, int n_in,
                              void* d_out, int out_size, void* d_ws, size_t ws_size,
                              hipStream_t stream) {
    const float* x       = (const float*)d_in[0];
    const int*   edge    = (const int*)d_in[1];   // JAX x64 disabled -> int32
    const int*   src     = edge;
    const int*   dst     = edge + NE;
    const int*   agent   = (const int*)d_in[2];
    const float* W1_rel  = (const float*)d_in[3];
    const float* b1_rel  = (const float*)d_in[4];
    const float* W1_root = (const float*)d_in[5];
    const float* W2_rel  = (const float*)d_in[6];
    const float* b2_rel  = (const float*)d_in[7];
    const float* W2_root = (const float*)d_in[8];
    const float* Wp1     = (const float*)d_in[9];
    const float* bp1     = (const float*)d_in[10];
    const float* Wp2     = (const float*)d_in[11];
    const float* bp2     = (const float*)d_in[12];
    const float* Wp3     = (const float*)d_in[13];
    const float* bp3     = (const float*)d_in[14];
    float* out = (float*)d_out;

    // workspace layout
    float* ws   = (float*)d_ws;
    float* aggr = ws;                               // 25.6 MB
    float* h    = ws + (size_t)NN * DIM;            // 25.6 MB
    float* z    = ws + (size_t)2 * NN * DIM;        // 25.6 MB
    int*   iws  = (int*)(ws + (size_t)3 * NN * DIM);
    int* deg    = iws;                  // NN
    int* off    = iws + NN;             // NN+1
    int* cursor = iws + 2 * NN + 1;     // NN
    int* eid    = iws + 3 * NN + 1;     // NE

    const int eb = (NE + 255) / 256;          // 3125
    const int conv_blocks = (NN + 63) / 64;   // 782
    const int gather_blocks = NN / 4;         // 12500

    // ---- CSR build (once; shared by both convs) ----
    hipMemsetAsync(deg, 0, NN * sizeof(int), stream);
    hist_kernel<<<eb, 256, 0, stream>>>(dst, deg);
    scan_kernel<<<1, 1024, 0, stream>>>(deg, off, cursor);
    fill_kernel<<<eb, 256, 0, stream>>>(src, dst, cursor, eid);

    // ---- conv1 ----
    gather_aggr_kernel<<<gather_blocks, 256, 0, stream>>>(x, off, eid, aggr);
    conv_kernel<<<conv_blocks, 256, 0, stream>>>(aggr, x, W1_rel, W1_root, b1_rel, h);
    // ---- conv2 ----
    gather_aggr_kernel<<<gather_blocks, 256, 0, stream>>>(h, off, eid, aggr);
    conv_kernel<<<conv_blocks, 256, 0, stream>>>(aggr, h, W2_rel, W2_root, b2_rel, z);
    // ---- agent MLP ----
    mlp_kernel<<<1024 / 8, 256, 0, stream>>>(z, agent, Wp1, bp1, Wp2, bp2, Wp3, bp3, out);
}

// Round 3
// 351.730 us; speedup vs baseline: 8.0886x; 1.3158x over previous
//
#include <hip/hip_runtime.h>

#define NN 50000
#define NE 800000
#define DIM 128
#define SCAN_BLOCKS ((NN + 255) / 256)   // 196

// ---------------- CSR build ----------------
__global__ __launch_bounds__(256)
void hist_kernel(const int* __restrict__ dst, int* __restrict__ deg) {
    int e = blockIdx.x * 256 + threadIdx.x;
    if (e < NE) atomicAdd(&deg[dst[e]], 1);
}

// stage 1: per-block exclusive scan of deg; block sums out
__global__ __launch_bounds__(256)
void scan1_kernel(const int* __restrict__ deg, int* __restrict__ exc,
                  int* __restrict__ bsum) {
    __shared__ int s[256];
    const int t = threadIdx.x;
    const int g = blockIdx.x * 256 + t;
    int v = (g < NN) ? deg[g] : 0;
    s[t] = v;
#pragma unroll
    for (int d = 1; d < 256; d <<= 1) {
        __syncthreads();
        int tmp = (t >= d) ? s[t - d] : 0;
        __syncthreads();
        s[t] += tmp;
    }
    __syncthreads();
    exc[g] = s[t] - v;
    if (t == 255) bsum[blockIdx.x] = s[255];
}

// stage 2: single tiny block scans the block sums (exclusive)
__global__ __launch_bounds__(256)
void scan2_kernel(int* __restrict__ bsum) {
    __shared__ int s[256];
    const int t = threadIdx.x;
    int v = (t < SCAN_BLOCKS) ? bsum[t] : 0;
    s[t] = v;
#pragma unroll
    for (int d = 1; d < 256; d <<= 1) {
        __syncthreads();
        int tmp = (t >= d) ? s[t - d] : 0;
        __syncthreads();
        s[t] += tmp;
    }
    __syncthreads();
    if (t < SCAN_BLOCKS) bsum[t] = s[t] - v;   // exclusive block offset
}

// stage 3: add block offsets, write off + cursor
__global__ __launch_bounds__(256)
void scan3_kernel(const int* __restrict__ exc, const int* __restrict__ bsum,
                  int* __restrict__ off, int* __restrict__ cursor) {
    const int g = blockIdx.x * 256 + threadIdx.x;
    if (g < NN) {
        int o = exc[g] + bsum[blockIdx.x];
        off[g] = o;
        cursor[g] = o;
    }
    if (g == 0) off[NN] = NE;
}

__global__ __launch_bounds__(256)
void fill_kernel(const int* __restrict__ src, const int* __restrict__ dst,
                 int* __restrict__ cursor, int* __restrict__ eid) {
    int e = blockIdx.x * 256 + threadIdx.x;
    if (e >= NE) return;
    int pos = atomicAdd(&cursor[dst[e]], 1);
    eid[pos] = src[e];
}

// ---------------- gather-aggregate: aggr[n] = sum_{e: dst=n} x[src[e]] ----
// one wave (64 lanes) per node; lane handles a float2 chunk (64*8B = 512B row)
__global__ __launch_bounds__(256)
void gather_aggr_kernel(const float* __restrict__ x,
                        const int* __restrict__ off,
                        const int* __restrict__ eid,
                        float* __restrict__ aggr) {
    const int node = blockIdx.x * 4 + (threadIdx.x >> 6);
    const int lane = threadIdx.x & 63;
    const int s = off[node];
    const int e = off[node + 1];
    const float2* __restrict__ x2 = (const float2*)x;
    float2 acc = make_float2(0.f, 0.f);
    int i = s;
    for (; i + 4 <= e; i += 4) {
        int n0 = eid[i], n1 = eid[i + 1], n2 = eid[i + 2], n3 = eid[i + 3];
        float2 v0 = x2[(size_t)n0 * 64 + lane];
        float2 v1 = x2[(size_t)n1 * 64 + lane];
        float2 v2 = x2[(size_t)n2 * 64 + lane];
        float2 v3 = x2[(size_t)n3 * 64 + lane];
        acc.x += (v0.x + v1.x) + (v2.x + v3.x);
        acc.y += (v0.y + v1.y) + (v2.y + v3.y);
    }
    for (; i < e; ++i) {
        int n = eid[i];
        float2 v = x2[(size_t)n * 64 + lane];
        acc.x += v.x;
        acc.y += v.y;
    }
    ((float2*)aggr)[(size_t)node * 64 + lane] = acc;
}

// ---------------- fused graph-conv GEMM ----------------
// Out[n][o] = relu( sum_k Aggr[n][k]*Wrel[o][k] + X[n][k]*Wroot[o][k] + bias[o] )
__global__ __launch_bounds__(256)
void conv_kernel(const float* __restrict__ Aggr,
                 const float* __restrict__ X,
                 const float* __restrict__ Wrel,
                 const float* __restrict__ Wroot,
                 const float* __restrict__ bias,
                 float* __restrict__ Out) {
    __shared__ __align__(16) float As[32][68];
    __shared__ __align__(16) float Bs[32][132];
    const int tid = threadIdx.x;
    const int tm = tid >> 4;
    const int tn = tid & 15;
    const int m_blk = blockIdx.x * 64;

    float acc[4][8];
#pragma unroll
    for (int i = 0; i < 4; ++i)
#pragma unroll
        for (int j = 0; j < 8; ++j) acc[i][j] = 0.f;

    const int lr = tid >> 3;
    const int lc = (tid & 7) * 4;

    for (int mat = 0; mat < 2; ++mat) {
        const float* A = mat ? X : Aggr;
        const float* W = mat ? Wroot : Wrel;
        for (int kb = 0; kb < 128; kb += 32) {
            __syncthreads();
#pragma unroll
            for (int rr = 0; rr < 2; ++rr) {
                int m = lr + rr * 32;
                int gm = m_blk + m;
                float4 v = make_float4(0.f, 0.f, 0.f, 0.f);
                if (gm < NN) v = *(const float4*)(A + (size_t)gm * DIM + kb + lc);
                As[lc + 0][m] = v.x;
                As[lc + 1][m] = v.y;
                As[lc + 2][m] = v.z;
                As[lc + 3][m] = v.w;
            }
#pragma unroll
            for (int rr = 0; rr < 4; ++rr) {
                int o = lr + rr * 32;
                float4 v = *(const float4*)(W + (size_t)o * DIM + kb + lc);
                Bs[lc + 0][o] = v.x;
                Bs[lc + 1][o] = v.y;
                Bs[lc + 2][o] = v.z;
                Bs[lc + 3][o] = v.w;
            }
            __syncthreads();
#pragma unroll
            for (int kk = 0; kk < 32; ++kk) {
                float4 a4 = *(const float4*)&As[kk][tm * 4];
                float4 b0 = *(const float4*)&Bs[kk][tn * 8];
                float4 b1 = *(const float4*)&Bs[kk][tn * 8 + 4];
                float a[4] = {a4.x, a4.y, a4.z, a4.w};
                float b[8] = {b0.x, b0.y, b0.z, b0.w, b1.x, b1.y, b1.z, b1.w};
#pragma unroll
                for (int i = 0; i < 4; ++i)
#pragma unroll
                    for (int j = 0; j < 8; ++j)
                        acc[i][j] += a[i] * b[j];
            }
        }
    }
    float4 bia0 = *(const float4*)(bias + tn * 8);
    float4 bia1 = *(const float4*)(bias + tn * 8 + 4);
#pragma unroll
    for (int i = 0; i < 4; ++i) {
        int gm = m_blk + tm * 4 + i;
        if (gm >= NN) continue;
        float4 v0, v1;
        v0.x = fmaxf(acc[i][0] + bia0.x, 0.f);
        v0.y = fmaxf(acc[i][1] + bia0.y, 0.f);
        v0.z = fmaxf(acc[i][2] + bia0.z, 0.f);
        v0.w = fmaxf(acc[i][3] + bia0.w, 0.f);
        v1.x = fmaxf(acc[i][4] + bia1.x, 0.f);
        v1.y = fmaxf(acc[i][5] + bia1.y, 0.f);
        v1.z = fmaxf(acc[i][6] + bia1.z, 0.f);
        v1.w = fmaxf(acc[i][7] + bia1.w, 0.f);
        *(float4*)(Out + (size_t)gm * DIM + tn * 8) = v0;
        *(float4*)(Out + (size_t)gm * DIM + tn * 8 + 4) = v1;
    }
}

// ---------------- fused agent MLP ----------------
__global__ __launch_bounds__(256)
void mlp_kernel(const float* __restrict__ Z,
                const int* __restrict__ agent_idx,
                const float* __restrict__ Wp1, const float* __restrict__ bp1,
                const float* __restrict__ Wp2, const float* __restrict__ bp2,
                const float* __restrict__ Wp3, const float* __restrict__ bp3,
                float* __restrict__ Out) {
    __shared__ __align__(16) float sel[8][132];
    __shared__ __align__(16) float m1[8][132];
    __shared__ __align__(16) float m2[8][132];
    const int tid = threadIdx.x;
    const int ab = blockIdx.x * 8;

    {
        int al = tid >> 5;
        int c = (tid & 31) * 4;
        int node = agent_idx[ab + al];
        float4 v = *(const float4*)(Z + (size_t)node * DIM + c);
        sel[al][c + 0] = v.x; sel[al][c + 1] = v.y;
        sel[al][c + 2] = v.z; sel[al][c + 3] = v.w;
    }
    __syncthreads();
    {
        int o = tid & 127;
        int g = tid >> 7;
        float acc[4] = {0.f, 0.f, 0.f, 0.f};
        for (int k = 0; k < 128; k += 4) {
            float4 w = *(const float4*)(Wp1 + (size_t)o * 128 + k);
#pragma unroll
            for (int a = 0; a < 4; ++a) {
                int aa = g * 4 + a;
                acc[a] += w.x * sel[aa][k] + w.y * sel[aa][k + 1]
                        + w.z * sel[aa][k + 2] + w.w * sel[aa][k + 3];
            }
        }
        float b = bp1[o];
#pragma unroll
        for (int a = 0; a < 4; ++a) m1[g * 4 + a][o] = fmaxf(acc[a] + b, 0.f);
    }
    __syncthreads();
    {
        int o = tid & 127;
        int g = tid >> 7;
        float acc[4] = {0.f, 0.f, 0.f, 0.f};
        for (int k = 0; k < 128; k += 4) {
            float4 w = *(const float4*)(Wp2 + (size_t)o * 128 + k);
#pragma unroll
            for (int a = 0; a < 4; ++a) {
                int aa = g * 4 + a;
                acc[a] += w.x * m1[aa][k] + w.y * m1[aa][k + 1]
                        + w.z * m1[aa][k + 2] + w.w * m1[aa][k + 3];
            }
        }
        float b = bp2[o];
#pragma unroll
        for (int a = 0; a < 4; ++a) m2[g * 4 + a][o] = fmaxf(acc[a] + b, 0.f);
    }
    __syncthreads();
    {
#pragma unroll
        for (int oo = 0; oo < 2; ++oo) {
            int o = tid + oo * 256;
            float acc[8] = {0.f, 0.f, 0.f, 0.f, 0.f, 0.f, 0.f, 0.f};
            for (int k = 0; k < 128; k += 4) {
                float4 w = *(const float4*)(Wp3 + (size_t)o * 128 + k);
#pragma unroll
                for (int a = 0; a < 8; ++a) {
                    acc[a] += w.x * m2[a][k] + w.y * m2[a][k + 1]
                            + w.z * m2[a][k + 2] + w.w * m2[a][k + 3];
                }
            }
            float b = bp3[o];
#pragma unroll
            for (int a = 0; a < 8; ++a)
                Out[(size_t)(ab + a) * 512 + o] = acc[a] + b;
        }
    }
}

extern "C" void kernel_launch(void* const* d_in, const int* in_sizes, int n_in,
                              void* d_out, int out_size, void* d_ws, size_t ws_size,
                              hipStream_t stream) {
    const float* x       = (const float*)d_in[0];
    const int*   edge    = (const int*)d_in[1];   // JAX x64 disabled -> int32
    const int*   src     = edge;
    const int*   dst     = edge + NE;
    const int*   agent   = (const int*)d_in[2];
    const float* W1_rel  = (const float*)d_in[3];
    const float* b1_rel  = (const float*)d_in[4];
    const float* W1_root = (const float*)d_in[5];
    const float* W2_rel  = (const float*)d_in[6];
    const float* b2_rel  = (const float*)d_in[7];
    const float* W2_root = (const float*)d_in[8];
    const float* Wp1     = (const float*)d_in[9];
    const float* bp1     = (const float*)d_in[10];
    const float* Wp2     = (const float*)d_in[11];
    const float* bp2     = (const float*)d_in[12];
    const float* Wp3     = (const float*)d_in[13];
    const float* bp3     = (const float*)d_in[14];
    float* out = (float*)d_out;

    // workspace layout
    float* ws   = (float*)d_ws;
    float* aggr = ws;                               // 25.6 MB
    float* h    = ws + (size_t)NN * DIM;            // 25.6 MB
    float* z    = ws + (size_t)2 * NN * DIM;        // 25.6 MB
    int*   iws  = (int*)(ws + (size_t)3 * NN * DIM);
    int* deg    = iws;                       // NN
    int* off    = iws + NN;                  // NN+1
    int* cursor = iws + 2 * NN + 1;          // NN
    int* exc    = iws + 3 * NN + 1;          // SCAN_BLOCKS*256 (padded)
    int* bsum   = exc + SCAN_BLOCKS * 256;   // SCAN_BLOCKS
    int* eid    = bsum + SCAN_BLOCKS;        // NE

    const int eb = (NE + 255) / 256;          // 3125
    const int conv_blocks = (NN + 63) / 64;   // 782
    const int gather_blocks = NN / 4;         // 12500

    // ---- CSR build (once; shared by both convs) ----
    hipMemsetAsync(deg, 0, NN * sizeof(int), stream);
    hist_kernel<<<eb, 256, 0, stream>>>(dst, deg);
    scan1_kernel<<<SCAN_BLOCKS, 256, 0, stream>>>(deg, exc, bsum);
    scan2_kernel<<<1, 256, 0, stream>>>(bsum);
    scan3_kernel<<<SCAN_BLOCKS, 256, 0, stream>>>(exc, bsum, off, cursor);
    fill_kernel<<<eb, 256, 0, stream>>>(src, dst, cursor, eid);

    // ---- conv1 ----
    gather_aggr_kernel<<<gather_blocks, 256, 0, stream>>>(x, off, eid, aggr);
    conv_kernel<<<conv_blocks, 256, 0, stream>>>(aggr, x, W1_rel, W1_root, b1_rel, h);
    // ---- conv2 ----
    gather_aggr_kernel<<<gather_blocks, 256, 0, stream>>>(h, off, eid, aggr);
    conv_kernel<<<conv_blocks, 256, 0, stream>>>(aggr, h, W2_rel, W2_root, b2_rel, z);
    // ---- agent MLP ----
    mlp_kernel<<<1024 / 8, 256, 0, stream>>>(z, agent, Wp1, bp1, Wp2, bp2, Wp3, bp3, out);
}

// Round 4
// 221.889 us; speedup vs baseline: 12.8218x; 1.5852x over previous
//
#include <hip/hip_runtime.h>

#define NN 50000
#define NE 800000
#define DIM 128
#define SCAN_BLOCKS ((NN + 255) / 256)   // 196

typedef __attribute__((ext_vector_type(8))) short bf16x8;
typedef __attribute__((ext_vector_type(8))) unsigned short u16x8;
typedef __attribute__((ext_vector_type(4))) float f32x4;

__device__ __forceinline__ unsigned short f2bf(float f) {
    unsigned int u = __builtin_bit_cast(unsigned int, f);
    u += 0x7fffu + ((u >> 16) & 1u);     // RNE
    return (unsigned short)(u >> 16);
}
__device__ __forceinline__ float bf2f(unsigned int lo16) {
    return __builtin_bit_cast(float, lo16 << 16);
}

// ---------------- f32 -> bf16 converters ----------------
__global__ __launch_bounds__(256)
void cvt_x_kernel(const float* __restrict__ s, unsigned short* __restrict__ d) {
    int base = (blockIdx.x * 256 + threadIdx.x) * 8;   // 3125*256*8 = 6,400,000 exact
    float4 a = *(const float4*)(s + base);
    float4 b = *(const float4*)(s + base + 4);
    u16x8 r;
    r[0] = f2bf(a.x); r[1] = f2bf(a.y); r[2] = f2bf(a.z); r[3] = f2bf(a.w);
    r[4] = f2bf(b.x); r[5] = f2bf(b.y); r[6] = f2bf(b.z); r[7] = f2bf(b.w);
    *(u16x8*)(d + base) = r;
}

__global__ __launch_bounds__(256)
void cvt_w_kernel(const float* __restrict__ s0, const float* __restrict__ s1,
                  const float* __restrict__ s2, const float* __restrict__ s3,
                  unsigned short* __restrict__ d0, unsigned short* __restrict__ d1,
                  unsigned short* __restrict__ d2, unsigned short* __restrict__ d3) {
    int which = blockIdx.x >> 3;                       // 8 blocks per 16384-elem matrix
    const float* s = which == 0 ? s0 : which == 1 ? s1 : which == 2 ? s2 : s3;
    unsigned short* d = which == 0 ? d0 : which == 1 ? d1 : which == 2 ? d2 : d3;
    int base = ((blockIdx.x & 7) * 256 + threadIdx.x) * 8;
    float4 a = *(const float4*)(s + base);
    float4 b = *(const float4*)(s + base + 4);
    u16x8 r;
    r[0] = f2bf(a.x); r[1] = f2bf(a.y); r[2] = f2bf(a.z); r[3] = f2bf(a.w);
    r[4] = f2bf(b.x); r[5] = f2bf(b.y); r[6] = f2bf(b.z); r[7] = f2bf(b.w);
    *(u16x8*)(d + base) = r;
}

// ---------------- CSR build ----------------
__global__ __launch_bounds__(256)
void hist_kernel(const int* __restrict__ dst, int* __restrict__ deg) {
    int e = blockIdx.x * 256 + threadIdx.x;
    if (e < NE) atomicAdd(&deg[dst[e]], 1);
}

__global__ __launch_bounds__(256)
void scan1_kernel(const int* __restrict__ deg, int* __restrict__ exc,
                  int* __restrict__ bsum) {
    __shared__ int s[256];
    const int t = threadIdx.x;
    const int g = blockIdx.x * 256 + t;
    int v = (g < NN) ? deg[g] : 0;
    s[t] = v;
#pragma unroll
    for (int d = 1; d < 256; d <<= 1) {
        __syncthreads();
        int tmp = (t >= d) ? s[t - d] : 0;
        __syncthreads();
        s[t] += tmp;
    }
    __syncthreads();
    exc[g] = s[t] - v;
    if (t == 255) bsum[blockIdx.x] = s[255];
}

__global__ __launch_bounds__(256)
void scan2_kernel(int* __restrict__ bsum) {
    __shared__ int s[256];
    const int t = threadIdx.x;
    int v = (t < SCAN_BLOCKS) ? bsum[t] : 0;
    s[t] = v;
#pragma unroll
    for (int d = 1; d < 256; d <<= 1) {
        __syncthreads();
        int tmp = (t >= d) ? s[t - d] : 0;
        __syncthreads();
        s[t] += tmp;
    }
    __syncthreads();
    if (t < SCAN_BLOCKS) bsum[t] = s[t] - v;
}

__global__ __launch_bounds__(256)
void scan3_kernel(const int* __restrict__ exc, const int* __restrict__ bsum,
                  int* __restrict__ off, int* __restrict__ cursor) {
    const int g = blockIdx.x * 256 + threadIdx.x;
    if (g < NN) {
        int o = exc[g] + bsum[blockIdx.x];
        off[g] = o;
        cursor[g] = o;
    }
    if (g == 0) off[NN] = NE;
}

__global__ __launch_bounds__(256)
void fill_kernel(const int* __restrict__ src, const int* __restrict__ dst,
                 int* __restrict__ cursor, int* __restrict__ eid) {
    int e = blockIdx.x * 256 + threadIdx.x;
    if (e >= NE) return;
    int pos = atomicAdd(&cursor[dst[e]], 1);
    eid[pos] = src[e];
}

// ---------------- bf16 gather-aggregate ----------------
// one wave per node; lane reads a 2-bf16 chunk (4 B) per neighbor row
__global__ __launch_bounds__(256)
void gather_bf16_kernel(const unsigned short* __restrict__ x,
                        const int* __restrict__ off,
                        const int* __restrict__ eid,
                        unsigned short* __restrict__ aggr) {
    const int node = blockIdx.x * 4 + (threadIdx.x >> 6);
    const int lane = threadIdx.x & 63;
    const int s = off[node];
    const int e = off[node + 1];
    float ax = 0.f, ay = 0.f;
    int i = s;
    for (; i + 4 <= e; i += 4) {
        int n0 = eid[i], n1 = eid[i + 1], n2 = eid[i + 2], n3 = eid[i + 3];
        unsigned int v0 = *(const unsigned int*)(x + (size_t)n0 * DIM + lane * 2);
        unsigned int v1 = *(const unsigned int*)(x + (size_t)n1 * DIM + lane * 2);
        unsigned int v2 = *(const unsigned int*)(x + (size_t)n2 * DIM + lane * 2);
        unsigned int v3 = *(const unsigned int*)(x + (size_t)n3 * DIM + lane * 2);
        ax += (bf2f(v0 & 0xffffu) + bf2f(v1 & 0xffffu))
            + (bf2f(v2 & 0xffffu) + bf2f(v3 & 0xffffu));
        ay += (bf2f(v0 >> 16) + bf2f(v1 >> 16)) + (bf2f(v2 >> 16) + bf2f(v3 >> 16));
    }
    for (; i < e; ++i) {
        int n = eid[i];
        unsigned int v = *(const unsigned int*)(x + (size_t)n * DIM + lane * 2);
        ax += bf2f(v & 0xffffu);
        ay += bf2f(v >> 16);
    }
    unsigned int packed = ((unsigned int)f2bf(ay) << 16) | f2bf(ax);
    *(unsigned int*)(aggr + (size_t)node * DIM + lane * 2) = packed;
}

// ---------------- MFMA graph-conv ----------------
// Out[n][o] = relu( Aggr[n]·Wrel[o] + X[n]·Wroot[o] + bias[o] ), all bf16 in/out
// block: 64 nodes x 128 outs; 4 waves, each a 16-row strip x 8 col-tiles
__global__ __launch_bounds__(256)
void conv_mfma_kernel(const unsigned short* __restrict__ A0,  // aggr bf16 [NN][128]
                      const unsigned short* __restrict__ A1,  // x/h bf16
                      const unsigned short* __restrict__ W0,  // Wrel bf16 [128][128]
                      const unsigned short* __restrict__ W1,  // Wroot bf16
                      const float* __restrict__ bias,
                      unsigned short* __restrict__ Out) {
    __shared__ __align__(16) unsigned short Wl[16384];   // 32 KB, XOR-swizzled
    const int tid = threadIdx.x;
    const int wave = tid >> 6;
    const int lane = tid & 63;
    const int m0 = blockIdx.x * 64 + wave * 16;
    const bool active = m0 < NN;      // 50000 % 16 == 0 -> strips are all-or-nothing
    const int col = lane & 15;
    const int kgrp = lane >> 4;       // 0..3
    const int swz = (col & 7) << 4;

    f32x4 acc[8];
#pragma unroll
    for (int t = 0; t < 8; ++t) acc[t] = (f32x4){0.f, 0.f, 0.f, 0.f};

    for (int mat = 0; mat < 2; ++mat) {
        const unsigned short* A = mat ? A1 : A0;
        const unsigned short* W = mat ? W1 : W0;
        __syncthreads();
        // stage W (128x128 bf16) into LDS, 16B chunks, swizzle byte ^= (row&7)<<4
#pragma unroll
        for (int i = 0; i < 8; ++i) {
            int chunk = i * 256 + tid;              // 0..2047
            int row = chunk >> 4;
            int b = (chunk * 16) ^ ((row & 7) << 4);
            *(uint4*)((char*)Wl + b) = *(const uint4*)(W + chunk * 8);
        }
        __syncthreads();
        if (active) {
            const int arow = m0 + col;
#pragma unroll
            for (int ks = 0; ks < 4; ++ks) {
                bf16x8 afrag = *(const bf16x8*)(A + (size_t)arow * DIM + ks * 32 + kgrp * 8);
                const int kb = ks * 64 + kgrp * 16;   // byte offset in a W row
#pragma unroll
                for (int t = 0; t < 8; ++t) {
                    int n = t * 16 + col;
                    int byteoff = (n * 256 + kb) ^ swz;
                    bf16x8 bfrag = *(const bf16x8*)((const char*)Wl + byteoff);
                    acc[t] = __builtin_amdgcn_mfma_f32_16x16x32_bf16(afrag, bfrag, acc[t], 0, 0, 0);
                }
            }
        }
    }
    if (active) {
        const int rgrp = lane >> 4;   // row = m0 + rgrp*4 + j
#pragma unroll
        for (int t = 0; t < 8; ++t) {
            int n = t * 16 + col;
            float bv = bias[n];
#pragma unroll
            for (int j = 0; j < 4; ++j) {
                float v = fmaxf(acc[t][j] + bv, 0.f);
                int row = m0 + rgrp * 4 + j;
                Out[(size_t)row * DIM + n] = f2bf(v);
            }
        }
    }
}

// ---------------- fused agent MLP (reads bf16 z, computes f32) ----------------
__global__ __launch_bounds__(256)
void mlp_kernel(const unsigned short* __restrict__ Z,
                const int* __restrict__ agent_idx,
                const float* __restrict__ Wp1, const float* __restrict__ bp1,
                const float* __restrict__ Wp2, const float* __restrict__ bp2,
                const float* __restrict__ Wp3, const float* __restrict__ bp3,
                float* __restrict__ Out) {
    __shared__ __align__(16) float sel[8][132];
    __shared__ __align__(16) float m1[8][132];
    __shared__ __align__(16) float m2[8][132];
    const int tid = threadIdx.x;
    const int ab = blockIdx.x * 8;

    {
        int al = tid >> 5;
        int c = (tid & 31) * 4;
        int node = agent_idx[ab + al];
        ushort4 v = *(const ushort4*)(Z + (size_t)node * DIM + c);
        sel[al][c + 0] = bf2f(v.x); sel[al][c + 1] = bf2f(v.y);
        sel[al][c + 2] = bf2f(v.z); sel[al][c + 3] = bf2f(v.w);
    }
    __syncthreads();
    {
        int o = tid & 127;
        int g = tid >> 7;
        float acc[4] = {0.f, 0.f, 0.f, 0.f};
        for (int k = 0; k < 128; k += 4) {
            float4 w = *(const float4*)(Wp1 + (size_t)o * 128 + k);
#pragma unroll
            for (int a = 0; a < 4; ++a) {
                int aa = g * 4 + a;
                acc[a] += w.x * sel[aa][k] + w.y * sel[aa][k + 1]
                        + w.z * sel[aa][k + 2] + w.w * sel[aa][k + 3];
            }
        }
        float b = bp1[o];
#pragma unroll
        for (int a = 0; a < 4; ++a) m1[g * 4 + a][o] = fmaxf(acc[a] + b, 0.f);
    }
    __syncthreads();
    {
        int o = tid & 127;
        int g = tid >> 7;
        float acc[4] = {0.f, 0.f, 0.f, 0.f};
        for (int k = 0; k < 128; k += 4) {
            float4 w = *(const float4*)(Wp2 + (size_t)o * 128 + k);
#pragma unroll
            for (int a = 0; a < 4; ++a) {
                int aa = g * 4 + a;
                acc[a] += w.x * m1[aa][k] + w.y * m1[aa][k + 1]
                        + w.z * m1[aa][k + 2] + w.w * m1[aa][k + 3];
            }
        }
        float b = bp2[o];
#pragma unroll
        for (int a = 0; a < 4; ++a) m2[g * 4 + a][o] = fmaxf(acc[a] + b, 0.f);
    }
    __syncthreads();
    {
#pragma unroll
        for (int oo = 0; oo < 2; ++oo) {
            int o = tid + oo * 256;
            float acc[8] = {0.f, 0.f, 0.f, 0.f, 0.f, 0.f, 0.f, 0.f};
            for (int k = 0; k < 128; k += 4) {
                float4 w = *(const float4*)(Wp3 + (size_t)o * 128 + k);
#pragma unroll
                for (int a = 0; a < 8; ++a) {
                    acc[a] += w.x * m2[a][k] + w.y * m2[a][k + 1]
                            + w.z * m2[a][k + 2] + w.w * m2[a][k + 3];
                }
            }
            float b = bp3[o];
#pragma unroll
            for (int a = 0; a < 8; ++a)
                Out[(size_t)(ab + a) * 512 + o] = acc[a] + b;
        }
    }
}

extern "C" void kernel_launch(void* const* d_in, const int* in_sizes, int n_in,
                              void* d_out, int out_size, void* d_ws, size_t ws_size,
                              hipStream_t stream) {
    const float* x       = (const float*)d_in[0];
    const int*   edge    = (const int*)d_in[1];   // JAX x64 disabled -> int32
    const int*   src     = edge;
    const int*   dst     = edge + NE;
    const int*   agent   = (const int*)d_in[2];
    const float* W1_rel  = (const float*)d_in[3];
    const float* b1_rel  = (const float*)d_in[4];
    const float* W1_root = (const float*)d_in[5];
    const float* W2_rel  = (const float*)d_in[6];
    const float* b2_rel  = (const float*)d_in[7];
    const float* W2_root = (const float*)d_in[8];
    const float* Wp1     = (const float*)d_in[9];
    const float* bp1     = (const float*)d_in[10];
    const float* Wp2     = (const float*)d_in[11];
    const float* bp2     = (const float*)d_in[12];
    const float* Wp3     = (const float*)d_in[13];
    const float* bp3     = (const float*)d_in[14];
    float* out = (float*)d_out;

    // workspace layout (all bf16 node buffers)
    const size_t NNDIM = (size_t)NN * DIM;
    unsigned short* xb  = (unsigned short*)d_ws;     // 12.8 MB
    unsigned short* ab  = xb + NNDIM;                // aggr (reused)
    unsigned short* hb  = ab + NNDIM;
    unsigned short* zb  = hb + NNDIM;
    unsigned short* w1r = zb + NNDIM;                // 4 x 32 KB
    unsigned short* w1o = w1r + 16384;
    unsigned short* w2r = w1o + 16384;
    unsigned short* w2o = w2r + 16384;
    int* iws    = (int*)(w2o + 16384);
    int* deg    = iws;                       // NN
    int* off    = iws + NN;                  // NN+1
    int* cursor = iws + 2 * NN + 1;          // NN
    int* exc    = iws + 3 * NN + 1;          // SCAN_BLOCKS*256
    int* bsum   = exc + SCAN_BLOCKS * 256;   // SCAN_BLOCKS
    int* eid    = bsum + SCAN_BLOCKS;        // NE

    const int eb = (NE + 255) / 256;          // 3125
    const int conv_blocks = (NN + 63) / 64;   // 782
    const int gather_blocks = NN / 4;         // 12500

    // ---- dtype conversion ----
    cvt_x_kernel<<<3125, 256, 0, stream>>>(x, xb);
    cvt_w_kernel<<<32, 256, 0, stream>>>(W1_rel, W1_root, W2_rel, W2_root,
                                         w1r, w1o, w2r, w2o);

    // ---- CSR build (once; shared by both convs) ----
    hipMemsetAsync(deg, 0, NN * sizeof(int), stream);
    hist_kernel<<<eb, 256, 0, stream>>>(dst, deg);
    scan1_kernel<<<SCAN_BLOCKS, 256, 0, stream>>>(deg, exc, bsum);
    scan2_kernel<<<1, 256, 0, stream>>>(bsum);
    scan3_kernel<<<SCAN_BLOCKS, 256, 0, stream>>>(exc, bsum, off, cursor);
    fill_kernel<<<eb, 256, 0, stream>>>(src, dst, cursor, eid);

    // ---- conv1 ----
    gather_bf16_kernel<<<gather_blocks, 256, 0, stream>>>(xb, off, eid, ab);
    conv_mfma_kernel<<<conv_blocks, 256, 0, stream>>>(ab, xb, w1r, w1o, b1_rel, hb);
    // ---- conv2 ----
    gather_bf16_kernel<<<gather_blocks, 256, 0, stream>>>(hb, off, eid, ab);
    conv_mfma_kernel<<<conv_blocks, 256, 0, stream>>>(ab, hb, w2r, w2o, b2_rel, zb);
    // ---- agent MLP ----
    mlp_kernel<<<1024 / 8, 256, 0, stream>>>(zb, agent, Wp1, bp1, Wp2, bp2, Wp3, bp3, out);
}